// Round 6
// baseline (154.727 us; speedup 1.0000x reference)
//
#include <hip/hip_runtime.h>
#include <math.h>

#define NHW 676               // 26*26
#define NB 256
#define NCELLS (NB * NHW)     // 173056 = 676 blocks * 256 threads
#define NBLK 676
#define NC 20                 // classes
#define NA 5                  // anchors

__device__ __forceinline__ float sigmoidf_(float x) {
    return 1.0f / (1.0f + __expf(-x));
}

// kernel: per-cell losses -> per-block float4 partials -> last block reduces
__global__ __launch_bounds__(256) void yolo_loss_kernel(
    const float* __restrict__ pred,    // (B, 125, 26, 26)
    const float* __restrict__ tgt,     // (B, 26, 26, 25)
    float* __restrict__ part,          // [NBLK*4] partials in d_ws
    unsigned int* __restrict__ counter,// 1 uint in d_ws (zeroed by memsetAsync)
    float* __restrict__ out)           // 4 floats
{
    __shared__ __align__(16) float stgt[256 * 25];   // 25.6 KB staged target
    __shared__ float sred[4][4];
    __shared__ int s_last;

    const int tid = threadIdx.x;
    const int t0  = blockIdx.x << 8;
    const int t   = t0 + tid;
    const int b   = t / NHW;
    const int hw  = t - b * NHW;
    const float* p = pred + (size_t)b * 125 * NHW + hw;   // channel stride NHW

    // ---- stage target block, coalesced float4 (1600 float4 / block) ----
    {
        const float4* g4 = (const float4*)(tgt + (size_t)t0 * 25);
        float4* s4 = (float4*)stgt;
        #pragma unroll
        for (int i = 0; i < 6; ++i) s4[i * 256 + tid] = g4[i * 256 + tid];
        if (tid < 64) s4[1536 + tid] = g4[1536 + tid];
    }

    // ---- 25 box/conf pred loads: NAMED SCALARS, no arrays -> no scratch ----
#define LD5(a) \
    float tc##a = p[((a)*25 + 20) * NHW]; \
    float tx##a = p[((a)*25 + 21) * NHW]; \
    float ty##a = p[((a)*25 + 22) * NHW]; \
    float tw##a = p[((a)*25 + 23) * NHW]; \
    float th##a = p[((a)*25 + 24) * NHW];
    LD5(0) LD5(1) LD5(2) LD5(3) LD5(4)
#undef LD5

    __syncthreads();
    const float* tg = stgt + tid * 25;   // stride 25 mod 32 -> conflict-free

    const float gconf = tg[20];
    const float gx = tg[21], gy = tg[22], gw = tg[23], gh = tg[24];
    const float g_x1 = gx - gw * 0.5f, g_x2 = gx + gw * 0.5f;
    const float g_y1 = gy - gh * 0.5f, g_y2 = gy + gh * 0.5f;
    const float g_area = gw * gh;

    float best_iou = -1.0f;
    int   best_a = 0;
    float bx = 0.0f, by = 0.0f, bw = 0.0f, bh = 0.0f, btc = 0.0f;

#define IOU_STEP(a, AWc, AHc) { \
    float px = sigmoidf_(tx##a); \
    float py = sigmoidf_(ty##a); \
    float pw = __expf(tw##a) * (AWc); \
    float ph = __expf(th##a) * (AHc); \
    float iw = fminf(px + pw * 0.5f, g_x2) - fmaxf(px - pw * 0.5f, g_x1); \
    float ih = fminf(py + ph * 0.5f, g_y2) - fmaxf(py - ph * 0.5f, g_y1); \
    iw = fmaxf(iw, 0.0f); ih = fmaxf(ih, 0.0f); \
    float inter = iw * ih; \
    float uni = pw * ph + g_area - inter; \
    float iou = inter / (uni + 1e-10f); \
    if (iou > best_iou) { /* strict >: first max wins, matches jnp.argmax */ \
        best_iou = iou; best_a = (a); \
        bx = px; by = py; bw = pw; bh = ph; btc = tc##a; \
    } }
    IOU_STEP(0, 1.3221f,  1.73145f)
    IOU_STEP(1, 3.19275f, 4.00944f)
    IOU_STEP(2, 5.05587f, 8.09892f)
    IOU_STEP(3, 9.47112f, 4.84053f)
    IOU_STEP(4, 11.2364f, 10.0071f)
#undef IOU_STEP

    const float bconf = sigmoidf_(btc);

    float box_l = 0.0f, conf_l = 0.0f, noobj_l = 0.0f, cls_l = 0.0f;

    if (gconf != 0.0f) {
        float dx = bx - gx, dy = by - gy, dw = bw - gw, dh = bh - gh;
        box_l = dx * dx + dy * dy + dw * dw + dh * dh;
        float dc = bconf - gconf;
        conf_l = dc * dc;

        // ---- class NLL for best anchor only: 20 NAMED scalar loads ----
        const float* pc = p + best_a * 25 * NHW;
#define LDC(k) float l##k = pc[(k) * NHW];
        LDC(0) LDC(1) LDC(2) LDC(3) LDC(4) LDC(5) LDC(6) LDC(7) LDC(8) LDC(9)
        LDC(10) LDC(11) LDC(12) LDC(13) LDC(14) LDC(15) LDC(16) LDC(17) LDC(18) LDC(19)
#undef LDC
        float m = l0;
#define MAXC(k) m = fmaxf(m, l##k);
        MAXC(1) MAXC(2) MAXC(3) MAXC(4) MAXC(5) MAXC(6) MAXC(7) MAXC(8) MAXC(9)
        MAXC(10) MAXC(11) MAXC(12) MAXC(13) MAXC(14) MAXC(15) MAXC(16) MAXC(17) MAXC(18) MAXC(19)
#undef MAXC
        float s = 0.0f, lsel = 0.0f;
#define ACC(k) { s += __expf(l##k - m); lsel = fmaf(tg[k], l##k, lsel); }
        ACC(0) ACC(1) ACC(2) ACC(3) ACC(4) ACC(5) ACC(6) ACC(7) ACC(8) ACC(9)
        ACC(10) ACC(11) ACC(12) ACC(13) ACC(14) ACC(15) ACC(16) ACC(17) ACC(18) ACC(19)
#undef ACC
        cls_l = -(lsel - m - __logf(s));
    } else {
        noobj_l = bconf * bconf;
    }

    // ---- wave (64-lane) reduction ----
    #pragma unroll
    for (int off = 32; off > 0; off >>= 1) {
        box_l   += __shfl_down(box_l,   off, 64);
        conf_l  += __shfl_down(conf_l,  off, 64);
        noobj_l += __shfl_down(noobj_l, off, 64);
        cls_l   += __shfl_down(cls_l,   off, 64);
    }

    const int wave = tid >> 6;
    const int lane = tid & 63;
    if (lane == 0) {
        sred[wave][0] = box_l;
        sred[wave][1] = conf_l;
        sred[wave][2] = noobj_l;
        sred[wave][3] = cls_l;
    }
    __syncthreads();

    if (tid == 0) {
        // agent-scope stores: visible across XCDs (per-XCD L2 non-coherent)
        float r0 = sred[0][0] + sred[1][0] + sred[2][0] + sred[3][0];
        float r1 = sred[0][1] + sred[1][1] + sred[2][1] + sred[3][1];
        float r2 = sred[0][2] + sred[1][2] + sred[2][2] + sred[3][2];
        float r3 = sred[0][3] + sred[1][3] + sred[2][3] + sred[3][3];
        float* pp = part + blockIdx.x * 4;
        __hip_atomic_store(pp + 0, r0, __ATOMIC_RELAXED, __HIP_MEMORY_SCOPE_AGENT);
        __hip_atomic_store(pp + 1, r1, __ATOMIC_RELAXED, __HIP_MEMORY_SCOPE_AGENT);
        __hip_atomic_store(pp + 2, r2, __ATOMIC_RELAXED, __HIP_MEMORY_SCOPE_AGENT);
        __hip_atomic_store(pp + 3, r3, __ATOMIC_RELAXED, __HIP_MEMORY_SCOPE_AGENT);
        __threadfence();
        unsigned int prev = atomicAdd(counter, 1u);
        s_last = (prev == NBLK - 1) ? 1 : 0;
    }
    __syncthreads();

    if (s_last) {
        // final reduction: wave w sums component w over 676 partials
        float s = 0.0f;
        for (int j = lane; j < NBLK; j += 64) {
            s += __hip_atomic_load(part + j * 4 + wave, __ATOMIC_RELAXED,
                                   __HIP_MEMORY_SCOPE_AGENT);
        }
        #pragma unroll
        for (int off = 32; off > 0; off >>= 1) {
            s += __shfl_down(s, off, 64);
        }
        if (lane == 0) {
            const float scale[4] = {5.0f / 256.0f, 1.0f / 256.0f,
                                    0.5f / 256.0f, 1.0f / 256.0f};
            out[wave] = s * scale[wave];
        }
    }
}

extern "C" void kernel_launch(void* const* d_in, const int* in_sizes, int n_in,
                              void* d_out, int out_size, void* d_ws, size_t ws_size,
                              hipStream_t stream) {
    const float* pred = (const float*)d_in[0];
    const float* tgt  = (const float*)d_in[1];
    float* out = (float*)d_out;
    float* part = (float*)d_ws;                              // NBLK*4 floats
    unsigned int* counter = (unsigned int*)((char*)d_ws + NBLK * 4 * sizeof(float));

    hipMemsetAsync(counter, 0, sizeof(unsigned int), stream);

    hipLaunchKernelGGL(yolo_loss_kernel, dim3(NCELLS / 256), dim3(256), 0, stream,
                       pred, tgt, part, counter, out);
}

// Round 7
// 131.626 us; speedup vs baseline: 1.1755x; 1.1755x over previous
//
#include <hip/hip_runtime.h>
#include <math.h>

#define NHW 676               // 26*26
#define NB 256
#define NCELLS (NB * NHW)     // 173056 cells
#define NBLK 338              // 338 blocks * 256 threads * 2 cells/thread
#define NC 20                 // classes
#define NA 5                  // anchors

__device__ __forceinline__ float sigmoidf_(float x) {
    return 1.0f / (1.0f + __expf(-x));
}

// ---------------- kernel 1: 2 cells/thread -> per-block float4 partials ----------------
__global__ __launch_bounds__(256) void yolo_loss_kernel(
    const float* __restrict__ pred,   // (B, 125, 26, 26)
    const float* __restrict__ tgt,    // (B, 26, 26, 25)
    float4* __restrict__ part)        // [NBLK] partials: box, conf, noobj, cls
{
    __shared__ __align__(16) float stgt[512 * 25];   // 50 KB staged target (512 cells)
    __shared__ float sred[4][4];

    const int tid = threadIdx.x;
    const int c0  = (blockIdx.x * 256 + tid) * 2;    // first of 2 cells (even)
    const int b   = c0 / NHW;
    const int hw  = c0 - b * NHW;                     // even; hw+1 <= 675 (NHW even)
    const float* p = pred + (size_t)b * 125 * NHW + hw;   // channel stride NHW

    // ---- stage target block: 512 cells * 25 floats = 3200 float4, coalesced ----
    {
        const float4* g4 = (const float4*)(tgt + (size_t)blockIdx.x * 512 * 25);
        float4* s4 = (float4*)stgt;
        #pragma unroll
        for (int i = 0; i < 12; ++i) s4[i * 256 + tid] = g4[i * 256 + tid];
        if (tid < 128) s4[3072 + tid] = g4[3072 + tid];
    }

    // ---- 25 float2 pred loads (both cells at once): NAMED SCALARS ----
#define LD5(a) \
    float2 tc##a = *(const float2*)(p + ((a)*25 + 20) * NHW); \
    float2 tx##a = *(const float2*)(p + ((a)*25 + 21) * NHW); \
    float2 ty##a = *(const float2*)(p + ((a)*25 + 22) * NHW); \
    float2 tw##a = *(const float2*)(p + ((a)*25 + 23) * NHW); \
    float2 th##a = *(const float2*)(p + ((a)*25 + 24) * NHW);
    LD5(0) LD5(1) LD5(2) LD5(3) LD5(4)
#undef LD5

    __syncthreads();

    float box_l = 0.0f, conf_l = 0.0f, noobj_l = 0.0f, cls_l = 0.0f;

    // ---- process the 2 cells; C = .x / .y component, off = 0 / 1 ----
#define CELL(C, off) { \
    const float* tg = stgt + (2 * tid + (off)) * 25; \
    const float gconf = tg[20]; \
    const float gx = tg[21], gy = tg[22], gw = tg[23], gh = tg[24]; \
    const float g_x1 = gx - gw * 0.5f, g_x2 = gx + gw * 0.5f; \
    const float g_y1 = gy - gh * 0.5f, g_y2 = gy + gh * 0.5f; \
    const float g_area = gw * gh; \
    float best_iou = -1.0f; \
    int   best_a = 0; \
    float bx = 0.0f, by = 0.0f, bw = 0.0f, bh = 0.0f, btc = 0.0f; \
    IOU_STEP(C, 0, 1.3221f,  1.73145f) \
    IOU_STEP(C, 1, 3.19275f, 4.00944f) \
    IOU_STEP(C, 2, 5.05587f, 8.09892f) \
    IOU_STEP(C, 3, 9.47112f, 4.84053f) \
    IOU_STEP(C, 4, 11.2364f, 10.0071f) \
    const float bconf = sigmoidf_(btc); \
    if (gconf != 0.0f) { \
        float dx = bx - gx, dy = by - gy, dw = bw - gw, dh = bh - gh; \
        box_l  += dx * dx + dy * dy + dw * dw + dh * dh; \
        float dc = bconf - gconf; \
        conf_l += dc * dc; \
        const float* pc = p + best_a * 25 * NHW + (off); \
        LDC(0) LDC(1) LDC(2) LDC(3) LDC(4) LDC(5) LDC(6) LDC(7) LDC(8) LDC(9) \
        LDC(10) LDC(11) LDC(12) LDC(13) LDC(14) LDC(15) LDC(16) LDC(17) LDC(18) LDC(19) \
        float m = l0; \
        MAXC(1) MAXC(2) MAXC(3) MAXC(4) MAXC(5) MAXC(6) MAXC(7) MAXC(8) MAXC(9) \
        MAXC(10) MAXC(11) MAXC(12) MAXC(13) MAXC(14) MAXC(15) MAXC(16) MAXC(17) MAXC(18) MAXC(19) \
        float s = 0.0f, lsel = 0.0f; \
        ACC(0) ACC(1) ACC(2) ACC(3) ACC(4) ACC(5) ACC(6) ACC(7) ACC(8) ACC(9) \
        ACC(10) ACC(11) ACC(12) ACC(13) ACC(14) ACC(15) ACC(16) ACC(17) ACC(18) ACC(19) \
        cls_l += -(lsel - m - __logf(s)); \
    } else { \
        noobj_l += bconf * bconf; \
    } }

#define IOU_STEP(C, a, AWc, AHc) { \
    float px = sigmoidf_(tx##a.C); \
    float py = sigmoidf_(ty##a.C); \
    float pw = __expf(tw##a.C) * (AWc); \
    float ph = __expf(th##a.C) * (AHc); \
    float iw = fminf(px + pw * 0.5f, g_x2) - fmaxf(px - pw * 0.5f, g_x1); \
    float ih = fminf(py + ph * 0.5f, g_y2) - fmaxf(py - ph * 0.5f, g_y1); \
    iw = fmaxf(iw, 0.0f); ih = fmaxf(ih, 0.0f); \
    float inter = iw * ih; \
    float uni = pw * ph + g_area - inter; \
    float iou = inter / (uni + 1e-10f); \
    if (iou > best_iou) { /* strict >: first max wins, matches jnp.argmax */ \
        best_iou = iou; best_a = (a); \
        bx = px; by = py; bw = pw; bh = ph; btc = tc##a.C; \
    } }
#define LDC(k) float l##k = pc[(k) * NHW];
#define MAXC(k) m = fmaxf(m, l##k);
#define ACC(k) { s += __expf(l##k - m); lsel = fmaf(tg[k], l##k, lsel); }

    CELL(x, 0)
    CELL(y, 1)

#undef ACC
#undef MAXC
#undef LDC
#undef IOU_STEP
#undef CELL

    // ---- wave (64-lane) reduction ----
    #pragma unroll
    for (int off = 32; off > 0; off >>= 1) {
        box_l   += __shfl_down(box_l,   off, 64);
        conf_l  += __shfl_down(conf_l,  off, 64);
        noobj_l += __shfl_down(noobj_l, off, 64);
        cls_l   += __shfl_down(cls_l,   off, 64);
    }

    const int wave = tid >> 6;
    const int lane = tid & 63;
    if (lane == 0) {
        sred[wave][0] = box_l;
        sred[wave][1] = conf_l;
        sred[wave][2] = noobj_l;
        sred[wave][3] = cls_l;
    }
    __syncthreads();
    if (tid == 0) {
        float4 r;
        r.x = sred[0][0] + sred[1][0] + sred[2][0] + sred[3][0];
        r.y = sred[0][1] + sred[1][1] + sred[2][1] + sred[3][1];
        r.z = sred[0][2] + sred[1][2] + sred[2][2] + sred[3][2];
        r.w = sred[0][3] + sred[1][3] + sred[2][3] + sred[3][3];
        part[blockIdx.x] = r;   // plain store, zero contention
    }
}

// ---------------- kernel 2: reduce NBLK float4 partials -> 4 scaled outputs ----------------
__global__ __launch_bounds__(256) void yolo_reduce_kernel(
    const float* __restrict__ part,   // NBLK * 4 floats
    float* __restrict__ out)          // 4 floats
{
    const int wave = threadIdx.x >> 6;   // component: 0=box 1=conf 2=noobj 3=cls
    const int lane = threadIdx.x & 63;

    float s = 0.0f;
    for (int j = lane; j < NBLK; j += 64) {
        s += part[j * 4 + wave];
    }
    #pragma unroll
    for (int off = 32; off > 0; off >>= 1) {
        s += __shfl_down(s, off, 64);
    }
    if (lane == 0) {
        const float scale[4] = {5.0f / 256.0f, 1.0f / 256.0f, 0.5f / 256.0f, 1.0f / 256.0f};
        out[wave] = s * scale[wave];
    }
}

extern "C" void kernel_launch(void* const* d_in, const int* in_sizes, int n_in,
                              void* d_out, int out_size, void* d_ws, size_t ws_size,
                              hipStream_t stream) {
    const float* pred = (const float*)d_in[0];
    const float* tgt  = (const float*)d_in[1];
    float* out = (float*)d_out;
    float4* part = (float4*)d_ws;

    hipLaunchKernelGGL(yolo_loss_kernel, dim3(NBLK), dim3(256), 0, stream,
                       pred, tgt, part);
    hipLaunchKernelGGL(yolo_reduce_kernel, dim3(1), dim3(256), 0, stream,
                       (const float*)part, out);
}